// Round 4
// baseline (158.531 us; speedup 1.0000x reference)
//
#include <hip/hip_runtime.h>
#include <math.h>

#define B_ 16
#define N_ 4096
#define K_ 16
#define ALPHA_ 1.05f

#define JSPLIT 4            // j-chunks per point (one wave each)
#define CHUNK (N_ / JSPLIT) // 1024 j's per wave
#define PTS 64              // points per block (one per lane)
#define BLK 256             // 4 waves
#define SENT_F 60000.0f     // sentinel > any real sq-dist (~300); f16-representable

#define SOA_BYTES (B_ * 3 * (N_ / 2) * 4)   // h2 = 4 B; 393,216 B

typedef __fp16 h2 __attribute__((ext_vector_type(2)));

struct H2x4 { h2 v[4]; };   // view of one float4 = 8 fp16 = 4 h2 pairs

// One 32-j batch of candidate coords held in registers (12 VGPR quads).
struct Tile { float4 x[4], y[4], z[4]; };

// ---------------------------------------------------------------------------
// Guaranteed-packed f16 ops via inline asm (VOP3P). Compiler was scalarizing
// the __builtin_elementwise path (~3x instr bloat, earlier counters).
// ---------------------------------------------------------------------------
__device__ __forceinline__ h2 h2min(h2 a, h2 b) {
    unsigned int ua = __builtin_bit_cast(unsigned int, a);
    unsigned int ub = __builtin_bit_cast(unsigned int, b);
    unsigned int r;
    asm("v_pk_min_f16 %0, %1, %2" : "=v"(r) : "v"(ua), "v"(ub));
    return __builtin_bit_cast(h2, r);
}
__device__ __forceinline__ h2 h2max(h2 a, h2 b) {
    unsigned int ua = __builtin_bit_cast(unsigned int, a);
    unsigned int ub = __builtin_bit_cast(unsigned int, b);
    unsigned int r;
    asm("v_pk_max_f16 %0, %1, %2" : "=v"(r) : "v"(ua), "v"(ub));
    return __builtin_bit_cast(h2, r);
}
__device__ __forceinline__ h2 h2add(h2 a, h2 b) {
    unsigned int ua = __builtin_bit_cast(unsigned int, a);
    unsigned int ub = __builtin_bit_cast(unsigned int, b);
    unsigned int r;
    asm("v_pk_add_f16 %0, %1, %2" : "=v"(r) : "v"(ua), "v"(ub));
    return __builtin_bit_cast(h2, r);
}
__device__ __forceinline__ h2 h2mul(h2 a, h2 b) {
    unsigned int ua = __builtin_bit_cast(unsigned int, a);
    unsigned int ub = __builtin_bit_cast(unsigned int, b);
    unsigned int r;
    asm("v_pk_mul_f16 %0, %1, %2" : "=v"(r) : "v"(ua), "v"(ub));
    return __builtin_bit_cast(h2, r);
}
__device__ __forceinline__ h2 h2fma(h2 a, h2 b, h2 c) {
    unsigned int ua = __builtin_bit_cast(unsigned int, a);
    unsigned int ub = __builtin_bit_cast(unsigned int, b);
    unsigned int uc = __builtin_bit_cast(unsigned int, c);
    unsigned int r;
    asm("v_pk_fma_f16 %0, %1, %2, %3" : "=v"(r) : "v"(ua), "v"(ub), "v"(uc));
    return __builtin_bit_cast(h2, r);
}

// ---------------------------------------------------------------------------
// Batcher odd-even merge sort, n=16, ascending: 63 CE, 2 streams per instr.
// ---------------------------------------------------------------------------
__device__ __forceinline__ void oems_sort16h(h2 v[16]) {
#pragma unroll
    for (int p = 1; p < 16; p <<= 1) {
#pragma unroll
        for (int k = p; k >= 1; k >>= 1) {
#pragma unroll
            for (int j = k & (p - 1); j + k < 16; j += 2 * k) {
#pragma unroll
                for (int i = 0; i < k; ++i) {
                    if (i + j + k < 16 &&
                        ((i + j) / (2 * p)) == ((i + j + k) / (2 * p))) {
                        const h2 a = v[i + j], b = v[i + j + k];
                        v[i + j]     = h2min(a, b);
                        v[i + j + k] = h2max(a, b);
                    }
                }
            }
        }
    }
}

// knn (sorted asc, packed) := lowest 16 of {knn, c} per half; c sorted asc.
__device__ __forceinline__ void merge16h(h2 knn[16], const h2 c[16]) {
#pragma unroll
    for (int i = 0; i < 16; ++i) knn[i] = h2min(knn[i], c[15 - i]);
#pragma unroll
    for (int j = 8; j > 0; j >>= 1) {
#pragma unroll
        for (int i = 0; i < 16; ++i) {
            const int l = i ^ j;
            if (l > i) {
                const h2 a = knn[i], b = knn[l];
                knn[i] = h2min(a, b);
                knn[l] = h2max(a, b);
            }
        }
    }
}

// f32 merge for the once-per-wave lo/hi combine (both sorted asc).
__device__ __forceinline__ void merge16f(float knn[16], const float c[16]) {
#pragma unroll
    for (int i = 0; i < 16; ++i) knn[i] = fminf(knn[i], c[15 - i]);
#pragma unroll
    for (int j = 8; j > 0; j >>= 1) {
#pragma unroll
        for (int i = 0; i < 16; ++i) {
            const int l = i ^ j;
            if (l > i) {
                const float a = knn[i], b = knn[l];
                knn[i] = fminf(a, b);
                knn[l] = fmaxf(a, b);
            }
        }
    }
}

// ---------------------------------------------------------------------------
// Prepack: f32 [B][N][3] -> negated f16 SoA planes [B][3][N/2] h2.
// Pairing: h2 = {-coord(2g), -coord(2g+1)} (even/odd consecutive points),
// identical grid (RTN) + layout to earlier rounds. Also zeroes out[0].
// ---------------------------------------------------------------------------
__global__ __launch_bounds__(256) void prepack_kernel(const float* __restrict__ pcs,
                                                      h2* __restrict__ soa,
                                                      float* __restrict__ out) {
    if (blockIdx.x == 0 && threadIdx.x == 0) out[0] = 0.0f;
    const int t = blockIdx.x * 256 + threadIdx.x;   // B*N/4 threads
    const int b = t >> 10;                          // N/4 = 1024 groups per batch
    const int g = t & 1023;                         // group of 4 points
    const float4* __restrict__ g4 =
        (const float4*)(pcs + (size_t)b * N_ * 3) + 3 * g;
    const float4 f0 = g4[0];
    const float4 f1 = g4[1];
    const float4 f2 = g4[2];
    h2* __restrict__ px = soa + (size_t)(b * 3 + 0) * (N_ / 2);
    h2* __restrict__ py = soa + (size_t)(b * 3 + 1) * (N_ / 2);
    h2* __restrict__ pz = soa + (size_t)(b * 3 + 2) * (N_ / 2);
    px[2 * g + 0] = h2{(__fp16)(-f0.x), (__fp16)(-f0.w)};
    px[2 * g + 1] = h2{(__fp16)(-f1.z), (__fp16)(-f2.y)};
    py[2 * g + 0] = h2{(__fp16)(-f0.y), (__fp16)(-f1.x)};
    py[2 * g + 1] = h2{(__fp16)(-f1.w), (__fp16)(-f2.z)};
    pz[2 * g + 0] = h2{(__fp16)(-f0.z), (__fp16)(-f1.y)};
    pz[2 * g + 1] = h2{(__fp16)(-f2.x), (__fp16)(-f2.w)};
}

// ---------------------------------------------------------------------------
// Tile load: issue 12 uniform global_load_dwordx4 for batch bb. Called one
// batch AHEAD of use so the ~200-300 cyc L1/L2 latency hides under the
// previous batch's ~500-cyc sort (per-wave double-buffer pipelining).
// ---------------------------------------------------------------------------
__device__ __forceinline__ void load_tile(Tile& T,
                                          const float4* __restrict__ xs4,
                                          const float4* __restrict__ ys4,
                                          const float4* __restrict__ zs4,
                                          int bb) {
#pragma unroll
    for (int r = 0; r < 4; ++r) {
        T.x[r] = xs4[bb * 4 + r];
        T.y[r] = ys4[bb * 4 + r];
        T.z[r] = zs4[bb * 4 + r];
    }
}

// ---------------------------------------------------------------------------
// Process one 32-j batch from a register tile (coords stored NEGATED).
// Self-exclusion is a rare wave-uniform patch branch (2 of 32 batches for
// one wave per block) -> hot sort/merge code is not duplicated per variant.
// ---------------------------------------------------------------------------
__device__ __forceinline__ void process_tile(const Tile& T, int jg0, int i,
                                             bool self_range,
                                             h2 qx, h2 qy, h2 qz,
                                             h2 knn[16]) {
    h2 c[16];
#pragma unroll
    for (int r = 0; r < 4; ++r) {
        const H2x4 hx = __builtin_bit_cast(H2x4, T.x[r]);
        const H2x4 hy = __builtin_bit_cast(H2x4, T.y[r]);
        const H2x4 hz = __builtin_bit_cast(H2x4, T.z[r]);
#pragma unroll
        for (int t = 0; t < 4; ++t) {
            const h2 dx = h2add(qx, hx.v[t]);
            const h2 dy = h2add(qy, hy.v[t]);
            const h2 dz = h2add(qz, hz.v[t]);
            h2 d = h2mul(dx, dx);
            d = h2fma(dy, dy, d);
            d = h2fma(dz, dz, d);
            c[r * 4 + t] = d;
        }
    }
    if (self_range) {          // wave-uniform, rare: patch self -> sentinel
#pragma unroll
        for (int s = 0; s < 16; ++s) {
            const int j0 = jg0 + 2 * s;
            if (j0 == i)     c[s].x = (__fp16)SENT_F;
            if (j0 + 1 == i) c[s].y = (__fp16)SENT_F;
        }
    }
    oems_sort16h(c);
    merge16h(knn, c);
}

// ---------------------------------------------------------------------------
// Kernel 1: per-point mean of 16 smallest non-self squared distances.
// Block = 256 threads = 4 waves. Wave w handles points [i0, i0+64) against
// j-chunk w (1024 j's = 32 batches), candidates streamed from global f16 SoA
// through a 2-deep register tile pipeline (load batch t+1 while sorting t).
// ---------------------------------------------------------------------------
__global__ __launch_bounds__(BLK, 4) void knn_kernel(const h2* __restrict__ soa,
                                                     const float* __restrict__ pcs,
                                                     float* __restrict__ knn_out) {
    __shared__ float lst[JSPLIT][PTS][K_ + 1];   // 17.4 KB, +1 pad

    const int b    = blockIdx.x >> 6;            // 64 blocks per batch
    const int grp  = blockIdx.x & 63;
    const int i0   = grp * PTS;
    const int lane = threadIdx.x & 63;
    const int w    = threadIdx.x >> 6;

    const float* __restrict__ src = pcs + (size_t)b * N_ * 3;

    const int i  = i0 + lane;
    const __fp16 qxh = (__fp16)src[3 * i + 0];   // RTN, same grid as candidates
    const __fp16 qyh = (__fp16)src[3 * i + 1];
    const __fp16 qzh = (__fp16)src[3 * i + 2];
    const h2 qx = {qxh, qxh}, qy = {qyh, qyh}, qz = {qzh, qzh};

    const h2 sent = {(__fp16)SENT_F, (__fp16)SENT_F};
    h2 knn[K_];
#pragma unroll
    for (int t = 0; t < K_; ++t) knn[t] = sent;

    const int jbase = w * CHUNK;
    const float4* __restrict__ soa4 = (const float4*)soa;
    const float4* __restrict__ xs4 = soa4 + (size_t)(b * 3 + 0) * (N_ / 8) + (jbase >> 3);
    const float4* __restrict__ ys4 = soa4 + (size_t)(b * 3 + 1) * (N_ / 8) + (jbase >> 3);
    const float4* __restrict__ zs4 = soa4 + (size_t)(b * 3 + 2) * (N_ / 8) + (jbase >> 3);

    const int NB = CHUNK / 32;                   // 32 batches
    Tile TA, TB;
    load_tile(TA, xs4, ys4, zs4, 0);

#pragma unroll 1
    for (int bb = 0; bb < NB; bb += 2) {
        load_tile(TB, xs4, ys4, zs4, bb + 1);                 // prefetch odd
        {
            const int jg0 = jbase + bb * 32;
            process_tile(TA, jg0, i, (unsigned)(jg0 - i0) < 64u,
                         qx, qy, qz, knn);
        }
        if (bb + 2 < NB) load_tile(TA, xs4, ys4, zs4, bb + 2); // prefetch even
        {
            const int jg0 = jbase + (bb + 1) * 32;
            process_tile(TB, jg0, i, (unsigned)(jg0 - i0) < 64u,
                         qx, qy, qz, knn);
        }
    }

    // ---- combine the two packed streams (lo/hi), once per wave
    float lo[K_], hi[K_];
#pragma unroll
    for (int t = 0; t < K_; ++t) { lo[t] = (float)knn[t].x; hi[t] = (float)knn[t].y; }
    merge16f(lo, hi);   // lowest 16 of 32, sorted asc

#pragma unroll
    for (int q = 0; q < K_; ++q) lst[w][lane][q] = lo[q];
    lst[w][lane][K_] = SENT_F;
    __syncthreads();

    // ---- 4-way merge of sorted lists, one thread per point (wave 0)
    if (threadIdx.x < PTS) {
        const int l = threadIdx.x;
        int p0 = 0, p1 = 0, p2 = 0, p3 = 0;
        float h0 = lst[0][l][0], h1 = lst[1][l][0];
        float h2v = lst[2][l][0], h3 = lst[3][l][0];
        float sm = 0.0f;
#pragma unroll
        for (int step = 0; step < K_; ++step) {
            const float m = fminf(fminf(h0, h1), fminf(h2v, h3));
            sm += m;
            if (h0 == m)       { h0 = lst[0][l][++p0]; }
            else if (h1 == m)  { h1 = lst[1][l][++p1]; }
            else if (h2v == m) { h2v = lst[2][l][++p2]; }
            else               { h3 = lst[3][l][++p3]; }
        }
        knn_out[b * N_ + i0 + l] = sm * (1.0f / (float)K_);
    }
}

// ---------------------------------------------------------------------------
// Block reduction helper (256 threads = 4 waves)
// ---------------------------------------------------------------------------
__device__ __forceinline__ float block_reduce_sum_256(float v, float* sbuf) {
    const int lane = threadIdx.x & 63;
    const int w    = threadIdx.x >> 6;
#pragma unroll
    for (int o = 32; o > 0; o >>= 1) v += __shfl_down(v, o, 64);
    __syncthreads();
    if (lane == 0) sbuf[w] = v;
    __syncthreads();
    return sbuf[0] + sbuf[1] + sbuf[2] + sbuf[3];
}

// ---------------------------------------------------------------------------
// Kernel 2: per-batch mean, std (two-pass), threshold, penalty partial sum,
// fused final: atomicAdd of scaled penalty into out[0] (zeroed by prepack).
// ---------------------------------------------------------------------------
__global__ __launch_bounds__(256) void stats_kernel(const float* __restrict__ knn_d,
                                                    float* __restrict__ out) {
    const int b   = blockIdx.x;
    const int tid = threadIdx.x;
    const float* __restrict__ x = knn_d + (size_t)b * N_;

    __shared__ float sbuf[4];

    float v[16];
    float s = 0.0f;
#pragma unroll
    for (int t = 0; t < 16; ++t) {
        v[t] = x[tid + t * 256];
        s += v[t];
    }
    const float total = block_reduce_sum_256(s, sbuf);
    const float mu = total * (1.0f / (float)N_);

    float vs = 0.0f;
#pragma unroll
    for (int t = 0; t < 16; ++t) {
        const float d = v[t] - mu;
        vs += d * d;
    }
    const float var    = block_reduce_sum_256(vs, sbuf) * (1.0f / (float)N_);
    const float thresh = mu + ALPHA_ * sqrtf(var);

    float p = 0.0f;
#pragma unroll
    for (int t = 0; t < 16; ++t) {
        if (v[t] > thresh) p += v[t];
    }
    const float psum = block_reduce_sum_256(p, sbuf);
    if (tid == 0) atomicAdd(out, psum * (1.0f / (float)(B_ * N_)));
}

extern "C" void kernel_launch(void* const* d_in, const int* in_sizes, int n_in,
                              void* d_out, int out_size, void* d_ws, size_t ws_size,
                              hipStream_t stream) {
    const float* pcs = (const float*)d_in[0];
    float* out = (float*)d_out;

    h2* soa      = (h2*)d_ws;                          // 393,216 B f16 SoA
    float* knn_d = (float*)((char*)d_ws + SOA_BYTES);  // B*N floats = 256 KB

    prepack_kernel<<<(B_ * N_ / 4) / 256, 256, 0, stream>>>(pcs, soa, out);
    knn_kernel<<<B_ * (N_ / PTS), BLK, 0, stream>>>(soa, pcs, knn_d);
    stats_kernel<<<B_, 256, 0, stream>>>(knn_d, out);
}

// Round 6
// 144.220 us; speedup vs baseline: 1.0992x; 1.0992x over previous
//
#include <hip/hip_runtime.h>
#include <math.h>

#define B_ 16
#define N_ 4096
#define K_ 16
#define ALPHA_ 1.05f

#define JSPLIT 4            // j-chunks per point (one wave each)
#define CHUNK (N_ / JSPLIT) // 1024 j's per wave
#define TJ 256              // j-tile staged in LDS per wave
#define PTS 64              // points per block (one per lane)
#define BLK 256             // 4 waves
#define SENT_F 60000.0f     // sentinel > any real sq-dist (~300); f16-representable

typedef __fp16 h2 __attribute__((ext_vector_type(2)));

struct H2x4 { h2 v[4]; };   // view of one float4 = 8 fp16 = 4 h2 pairs

// ---------------------------------------------------------------------------
// Guaranteed-packed f16 ops via inline asm (VOP3P). Compiler was scalarizing
// the __builtin_elementwise path (~3x instr bloat, round-7 counters).
// ---------------------------------------------------------------------------
__device__ __forceinline__ h2 h2min(h2 a, h2 b) {
    unsigned int ua = __builtin_bit_cast(unsigned int, a);
    unsigned int ub = __builtin_bit_cast(unsigned int, b);
    unsigned int r;
    asm("v_pk_min_f16 %0, %1, %2" : "=v"(r) : "v"(ua), "v"(ub));
    return __builtin_bit_cast(h2, r);
}
__device__ __forceinline__ h2 h2max(h2 a, h2 b) {
    unsigned int ua = __builtin_bit_cast(unsigned int, a);
    unsigned int ub = __builtin_bit_cast(unsigned int, b);
    unsigned int r;
    asm("v_pk_max_f16 %0, %1, %2" : "=v"(r) : "v"(ua), "v"(ub));
    return __builtin_bit_cast(h2, r);
}
__device__ __forceinline__ h2 h2add(h2 a, h2 b) {
    unsigned int ua = __builtin_bit_cast(unsigned int, a);
    unsigned int ub = __builtin_bit_cast(unsigned int, b);
    unsigned int r;
    asm("v_pk_add_f16 %0, %1, %2" : "=v"(r) : "v"(ua), "v"(ub));
    return __builtin_bit_cast(h2, r);
}
__device__ __forceinline__ h2 h2mul(h2 a, h2 b) {
    unsigned int ua = __builtin_bit_cast(unsigned int, a);
    unsigned int ub = __builtin_bit_cast(unsigned int, b);
    unsigned int r;
    asm("v_pk_mul_f16 %0, %1, %2" : "=v"(r) : "v"(ua), "v"(ub));
    return __builtin_bit_cast(h2, r);
}
__device__ __forceinline__ h2 h2fma(h2 a, h2 b, h2 c) {
    unsigned int ua = __builtin_bit_cast(unsigned int, a);
    unsigned int ub = __builtin_bit_cast(unsigned int, b);
    unsigned int uc = __builtin_bit_cast(unsigned int, c);
    unsigned int r;
    asm("v_pk_fma_f16 %0, %1, %2, %3" : "=v"(r) : "v"(ua), "v"(ub), "v"(uc));
    return __builtin_bit_cast(h2, r);
}

// ---------------------------------------------------------------------------
// Batcher odd-even merge sort, n=16, ascending: 63 CE, 2 streams per instr.
// ---------------------------------------------------------------------------
__device__ __forceinline__ void oems_sort16h(h2 v[16]) {
#pragma unroll
    for (int p = 1; p < 16; p <<= 1) {
#pragma unroll
        for (int k = p; k >= 1; k >>= 1) {
#pragma unroll
            for (int j = k & (p - 1); j + k < 16; j += 2 * k) {
#pragma unroll
                for (int i = 0; i < k; ++i) {
                    if (i + j + k < 16 &&
                        ((i + j) / (2 * p)) == ((i + j + k) / (2 * p))) {
                        const h2 a = v[i + j], b = v[i + j + k];
                        v[i + j]     = h2min(a, b);
                        v[i + j + k] = h2max(a, b);
                    }
                }
            }
        }
    }
}

// knn (sorted asc, packed) := lowest 16 of {knn, c} per half; c sorted asc.
__device__ __forceinline__ void merge16h(h2 knn[16], const h2 c[16]) {
#pragma unroll
    for (int i = 0; i < 16; ++i) knn[i] = h2min(knn[i], c[15 - i]);
#pragma unroll
    for (int j = 8; j > 0; j >>= 1) {
#pragma unroll
        for (int i = 0; i < 16; ++i) {
            const int l = i ^ j;
            if (l > i) {
                const h2 a = knn[i], b = knn[l];
                knn[i] = h2min(a, b);
                knn[l] = h2max(a, b);
            }
        }
    }
}

// f32 merge for the once-per-wave lo/hi combine (both sorted asc).
__device__ __forceinline__ void merge16f(float knn[16], const float c[16]) {
#pragma unroll
    for (int i = 0; i < 16; ++i) knn[i] = fminf(knn[i], c[15 - i]);
#pragma unroll
    for (int j = 8; j > 0; j >>= 1) {
#pragma unroll
        for (int i = 0; i < 16; ++i) {
            const int l = i ^ j;
            if (l > i) {
                const float a = knn[i], b = knn[l];
                knn[i] = fminf(a, b);
                knn[l] = fmaxf(a, b);
            }
        }
    }
}

// ---------------------------------------------------------------------------
// Process one 256-j f16-SoA tile (coords stored NEGATED): 8 batches of 32 j.
// dx = q + (-x) -> v_pk_add; d = dx*dx; d += dy*dy; d += dz*dz (pk_fma).
// ---------------------------------------------------------------------------
template <bool HAS_SELF>
__device__ __forceinline__ void process_tile(const float4* __restrict__ xs4,
                                             const float4* __restrict__ ys4,
                                             const float4* __restrict__ zs4,
                                             int jg0, int i,
                                             h2 qx, h2 qy, h2 qz,
                                             h2 knn[16]) {
#pragma unroll 1
    for (int bb = 0; bb < TJ / 32; ++bb) {
        h2 c[16];
#pragma unroll
        for (int r = 0; r < 4; ++r) {
            const H2x4 hx = __builtin_bit_cast(H2x4, xs4[bb * 4 + r]); // b128 broadcast
            const H2x4 hy = __builtin_bit_cast(H2x4, ys4[bb * 4 + r]);
            const H2x4 hz = __builtin_bit_cast(H2x4, zs4[bb * 4 + r]);
#pragma unroll
            for (int t = 0; t < 4; ++t) {
                const h2 dx = h2add(qx, hx.v[t]);
                const h2 dy = h2add(qy, hy.v[t]);
                const h2 dz = h2add(qz, hz.v[t]);
                h2 d = h2mul(dx, dx);
                d = h2fma(dy, dy, d);
                d = h2fma(dz, dz, d);
                if (HAS_SELF) {
                    const int j0 = jg0 + bb * 32 + r * 8 + 2 * t;
                    if (j0 == i)     d.x = (__fp16)SENT_F;
                    if (j0 + 1 == i) d.y = (__fp16)SENT_F;
                }
                c[r * 4 + t] = d;
            }
        }
        oems_sort16h(c);
        merge16h(knn, c);
    }
}

// ---------------------------------------------------------------------------
// Block reduction helper (256 threads = 4 waves)
// ---------------------------------------------------------------------------
__device__ __forceinline__ float block_reduce_sum_256(float v, float* sbuf) {
    const int lane = threadIdx.x & 63;
    const int w    = threadIdx.x >> 6;
#pragma unroll
    for (int o = 32; o > 0; o >>= 1) v += __shfl_down(v, o, 64);
    __syncthreads();
    if (lane == 0) sbuf[w] = v;
    __syncthreads();
    return sbuf[0] + sbuf[1] + sbuf[2] + sbuf[3];
}

// ---------------------------------------------------------------------------
// Kernel: per-point mean of 16 smallest non-self squared distances, with the
// per-batch stats FUSED via last-block-done: the 64th block of each batch to
// finish computes that batch's mean/std/threshold/penalty; the 16th batch to
// finish stats plain-stores out[0]. Eliminates the stats dispatch + memset of
// out (45 us of dispatch/gap overhead at round-0's 134 us total).
// knn core is byte-identical to the proven round-0 kernel (89 us, absmax 0).
// ---------------------------------------------------------------------------
__global__ __launch_bounds__(BLK, 4) void knn_kernel(const float* __restrict__ pcs,
                                                     float* __restrict__ knn_d,
                                                     float* __restrict__ psum,
                                                     unsigned* __restrict__ done1,
                                                     unsigned* __restrict__ done2,
                                                     float* __restrict__ out) {
    __shared__ float4 s[JSPLIT][3][TJ / 8];      // f16 SoA x/y/z, 6 KB
    __shared__ float  lst[JSPLIT][PTS][K_ + 1];  // 17.4 KB, +1 pad
    __shared__ float  sbuf[4];
    __shared__ unsigned slast;

    const int b    = blockIdx.x >> 6;            // 64 blocks per batch
    const int grp  = blockIdx.x & 63;
    const int i0   = grp * PTS;
    const int lane = threadIdx.x & 63;
    const int w    = threadIdx.x >> 6;

    const float* __restrict__ src = pcs + (size_t)b * N_ * 3;

    const int i  = i0 + lane;
    const __fp16 qxh = (__fp16)src[3 * i + 0];   // RTN, same grid as candidates
    const __fp16 qyh = (__fp16)src[3 * i + 1];
    const __fp16 qzh = (__fp16)src[3 * i + 2];
    const h2 qx = {qxh, qxh}, qy = {qyh, qyh}, qz = {qzh, qzh};

    const h2 sent = {(__fp16)SENT_F, (__fp16)SENT_F};
    h2 knn[K_];
#pragma unroll
    for (int t = 0; t < K_; ++t) knn[t] = sent;

    const int jbase = w * CHUNK;
    h2* sxw = (h2*)&s[w][0][0];
    h2* syw = (h2*)&s[w][1][0];
    h2* szw = (h2*)&s[w][2][0];

#pragma unroll 1
    for (int t0 = 0; t0 < CHUNK; t0 += TJ) {
        // ---- stage: lane l loads 4 points (3 float4 = 12 floats), converts
        //      NEGATED (RTN) to f16, writes paired h2 SoA.
        const float4* __restrict__ g4 =
            (const float4*)(src + (size_t)(jbase + t0) * 3);
        const float4 f0 = g4[3 * lane + 0];
        const float4 f1 = g4[3 * lane + 1];
        const float4 f2 = g4[3 * lane + 2];
        sxw[2 * lane + 0] = h2{(__fp16)(-f0.x), (__fp16)(-f0.w)};
        sxw[2 * lane + 1] = h2{(__fp16)(-f1.z), (__fp16)(-f2.y)};
        syw[2 * lane + 0] = h2{(__fp16)(-f0.y), (__fp16)(-f1.x)};
        syw[2 * lane + 1] = h2{(__fp16)(-f1.w), (__fp16)(-f2.z)};
        szw[2 * lane + 0] = h2{(__fp16)(-f0.z), (__fp16)(-f1.y)};
        szw[2 * lane + 1] = h2{(__fp16)(-f2.x), (__fp16)(-f2.w)};
        // wave-private quadrant; lanes lockstep within the wave, compiler
        // inserts lgkmcnt waits for the write->read dependence.

        const int jg0 = jbase + t0;
        if ((i0 >> 8) == (jg0 >> 8)) {
            process_tile<true >(&s[w][0][0], &s[w][1][0], &s[w][2][0],
                                jg0, i, qx, qy, qz, knn);
        } else {
            process_tile<false>(&s[w][0][0], &s[w][1][0], &s[w][2][0],
                                jg0, i, qx, qy, qz, knn);
        }
    }

    // ---- combine the two packed streams (lo/hi), once per wave
    float lo[K_], hi[K_];
#pragma unroll
    for (int t = 0; t < K_; ++t) { lo[t] = (float)knn[t].x; hi[t] = (float)knn[t].y; }
    merge16f(lo, hi);   // lowest 16 of 32, sorted asc

#pragma unroll
    for (int q = 0; q < K_; ++q) lst[w][lane][q] = lo[q];
    lst[w][lane][K_] = SENT_F;
    __syncthreads();

    // ---- 4-way merge of sorted lists, one thread per point (wave 0)
    if (threadIdx.x < PTS) {
        const int l = threadIdx.x;
        int p0 = 0, p1 = 0, p2 = 0, p3 = 0;
        float h0 = lst[0][l][0], h1 = lst[1][l][0];
        float h2v = lst[2][l][0], h3 = lst[3][l][0];
        float sm = 0.0f;
#pragma unroll
        for (int step = 0; step < K_; ++step) {
            const float m = fminf(fminf(h0, h1), fminf(h2v, h3));
            sm += m;
            if (h0 == m)       { h0 = lst[0][l][++p0]; }
            else if (h1 == m)  { h1 = lst[1][l][++p1]; }
            else if (h2v == m) { h2v = lst[2][l][++p2]; }
            else               { h3 = lst[3][l][++p3]; }
        }
        knn_d[b * N_ + i0 + l] = sm * (1.0f / (float)K_);
    }

    // ================= fused per-batch stats (last-block-done) =============
    __syncthreads();                  // drains vmcnt: knn_d stores complete
    if (threadIdx.x == 0) {
        __threadfence();              // release: publish knn_d device-wide
        const unsigned old = atomicAdd(&done1[b], 1u);
        slast = (old == 63u) ? 1u : 0u;
    }
    __syncthreads();
    if (slast) {
        __threadfence();              // acquire: see all 64 blocks' knn_d
        const int tid = threadIdx.x;
        const float* __restrict__ x = knn_d + (size_t)b * N_;

        float v[16];
        float sacc = 0.0f;
#pragma unroll
        for (int t = 0; t < 16; ++t) {
            v[t] = x[tid + t * 256];
            sacc += v[t];
        }
        const float total = block_reduce_sum_256(sacc, sbuf);
        const float mu = total * (1.0f / (float)N_);

        float vs = 0.0f;
#pragma unroll
        for (int t = 0; t < 16; ++t) {
            const float d = v[t] - mu;
            vs += d * d;
        }
        const float var    = block_reduce_sum_256(vs, sbuf) * (1.0f / (float)N_);
        const float thresh = mu + ALPHA_ * sqrtf(var);

        float p = 0.0f;
#pragma unroll
        for (int t = 0; t < 16; ++t) {
            if (v[t] > thresh) p += v[t];
        }
        const float ps = block_reduce_sum_256(p, sbuf);

        if (threadIdx.x == 0) {
            psum[b] = ps;
            __threadfence();          // release psum[b]
            const unsigned o2 = atomicAdd(done2, 1u);
            if (o2 == 15u) {          // last batch finished stats
                __threadfence();      // acquire all psum
                float sall = 0.0f;
#pragma unroll
                for (int k = 0; k < B_; ++k) sall += psum[k];
                out[0] = sall * (1.0f / (float)(B_ * N_));  // plain store
            }
        }
    }
}

extern "C" void kernel_launch(void* const* d_in, const int* in_sizes, int n_in,
                              void* d_out, int out_size, void* d_ws, size_t ws_size,
                              hipStream_t stream) {
    const float* pcs = (const float*)d_in[0];
    float* out = (float*)d_out;

    // workspace layout
    float*    knn_d = (float*)d_ws;                          // 256 KB
    float*    psum  = (float*)((char*)d_ws + (size_t)B_ * N_ * 4); // 64 B
    unsigned* done1 = (unsigned*)(psum + B_);                // 64 B
    unsigned* done2 = done1 + B_;                            // 4 B

    // zero only the completion counters (68 B); psum/out need no init
    (void)hipMemsetAsync(done1, 0, (B_ + 1) * sizeof(unsigned), stream);
    knn_kernel<<<B_ * (N_ / PTS), BLK, 0, stream>>>(pcs, knn_d, psum,
                                                    done1, done2, out);
}

// Round 8
// 138.778 us; speedup vs baseline: 1.1423x; 1.0392x over previous
//
#include <hip/hip_runtime.h>
#include <math.h>

#define B_ 16
#define N_ 4096
#define K_ 16
#define ALPHA_ 1.05f

#define JSPLIT 8            // j-chunks per point (one wave each)
#define CHUNK (N_ / JSPLIT) // 512 j's per wave
#define TJ 256              // j-tile staged in LDS per wave
#define PTS 64              // points per block (one per lane)
#define BLK 512             // 8 waves; LDS 29.7 KB -> 4 blocks/CU = 32 waves/CU
#define SENT_F 60000.0f     // sentinel > any real sq-dist (~300); f16-representable

typedef __fp16 h2 __attribute__((ext_vector_type(2)));

struct H2x4 { h2 v[4]; };   // view of one float4 = 8 fp16 = 4 h2 pairs

// ---------------------------------------------------------------------------
// Guaranteed-packed f16 ops via inline asm (VOP3P). Compiler was scalarizing
// the __builtin_elementwise path (~3x instr bloat, earlier counters).
// ---------------------------------------------------------------------------
__device__ __forceinline__ h2 h2min(h2 a, h2 b) {
    unsigned int ua = __builtin_bit_cast(unsigned int, a);
    unsigned int ub = __builtin_bit_cast(unsigned int, b);
    unsigned int r;
    asm("v_pk_min_f16 %0, %1, %2" : "=v"(r) : "v"(ua), "v"(ub));
    return __builtin_bit_cast(h2, r);
}
__device__ __forceinline__ h2 h2max(h2 a, h2 b) {
    unsigned int ua = __builtin_bit_cast(unsigned int, a);
    unsigned int ub = __builtin_bit_cast(unsigned int, b);
    unsigned int r;
    asm("v_pk_max_f16 %0, %1, %2" : "=v"(r) : "v"(ua), "v"(ub));
    return __builtin_bit_cast(h2, r);
}
__device__ __forceinline__ h2 h2add(h2 a, h2 b) {
    unsigned int ua = __builtin_bit_cast(unsigned int, a);
    unsigned int ub = __builtin_bit_cast(unsigned int, b);
    unsigned int r;
    asm("v_pk_add_f16 %0, %1, %2" : "=v"(r) : "v"(ua), "v"(ub));
    return __builtin_bit_cast(h2, r);
}
__device__ __forceinline__ h2 h2mul(h2 a, h2 b) {
    unsigned int ua = __builtin_bit_cast(unsigned int, a);
    unsigned int ub = __builtin_bit_cast(unsigned int, b);
    unsigned int r;
    asm("v_pk_mul_f16 %0, %1, %2" : "=v"(r) : "v"(ua), "v"(ub));
    return __builtin_bit_cast(h2, r);
}
__device__ __forceinline__ h2 h2fma(h2 a, h2 b, h2 c) {
    unsigned int ua = __builtin_bit_cast(unsigned int, a);
    unsigned int ub = __builtin_bit_cast(unsigned int, b);
    unsigned int uc = __builtin_bit_cast(unsigned int, c);
    unsigned int r;
    asm("v_pk_fma_f16 %0, %1, %2, %3" : "=v"(r) : "v"(ua), "v"(ub), "v"(uc));
    return __builtin_bit_cast(h2, r);
}

// ---------------------------------------------------------------------------
// Batcher odd-even merge sort, n=16, ascending: 63 CE, 2 streams per instr.
// ---------------------------------------------------------------------------
__device__ __forceinline__ void oems_sort16h(h2 v[16]) {
#pragma unroll
    for (int p = 1; p < 16; p <<= 1) {
#pragma unroll
        for (int k = p; k >= 1; k >>= 1) {
#pragma unroll
            for (int j = k & (p - 1); j + k < 16; j += 2 * k) {
#pragma unroll
                for (int i = 0; i < k; ++i) {
                    if (i + j + k < 16 &&
                        ((i + j) / (2 * p)) == ((i + j + k) / (2 * p))) {
                        const h2 a = v[i + j], b = v[i + j + k];
                        v[i + j]     = h2min(a, b);
                        v[i + j + k] = h2max(a, b);
                    }
                }
            }
        }
    }
}

// knn (sorted asc, packed) := lowest 16 of {knn, c} per half; c sorted asc.
__device__ __forceinline__ void merge16h(h2 knn[16], const h2 c[16]) {
#pragma unroll
    for (int i = 0; i < 16; ++i) knn[i] = h2min(knn[i], c[15 - i]);
#pragma unroll
    for (int j = 8; j > 0; j >>= 1) {
#pragma unroll
        for (int i = 0; i < 16; ++i) {
            const int l = i ^ j;
            if (l > i) {
                const h2 a = knn[i], b = knn[l];
                knn[i] = h2min(a, b);
                knn[l] = h2max(a, b);
            }
        }
    }
}

// f32 merge for the once-per-wave lo/hi combine (both sorted asc).
__device__ __forceinline__ void merge16f(float knn[16], const float c[16]) {
#pragma unroll
    for (int i = 0; i < 16; ++i) knn[i] = fminf(knn[i], c[15 - i]);
#pragma unroll
    for (int j = 8; j > 0; j >>= 1) {
#pragma unroll
        for (int i = 0; i < 16; ++i) {
            const int l = i ^ j;
            if (l > i) {
                const float a = knn[i], b = knn[l];
                knn[i] = fminf(a, b);
                knn[l] = fmaxf(a, b);
            }
        }
    }
}

// ---------------------------------------------------------------------------
// Process one 256-j f16-SoA tile (coords stored NEGATED): 8 batches of 32 j.
// dx = q + (-x) -> v_pk_add; d = dx*dx; d += dy*dy; d += dz*dz (pk_fma).
// ---------------------------------------------------------------------------
template <bool HAS_SELF>
__device__ __forceinline__ void process_tile(const float4* __restrict__ xs4,
                                             const float4* __restrict__ ys4,
                                             const float4* __restrict__ zs4,
                                             int jg0, int i,
                                             h2 qx, h2 qy, h2 qz,
                                             h2 knn[16]) {
#pragma unroll 1
    for (int bb = 0; bb < TJ / 32; ++bb) {
        h2 c[16];
#pragma unroll
        for (int r = 0; r < 4; ++r) {
            const H2x4 hx = __builtin_bit_cast(H2x4, xs4[bb * 4 + r]); // b128 broadcast
            const H2x4 hy = __builtin_bit_cast(H2x4, ys4[bb * 4 + r]);
            const H2x4 hz = __builtin_bit_cast(H2x4, zs4[bb * 4 + r]);
#pragma unroll
            for (int t = 0; t < 4; ++t) {
                const h2 dx = h2add(qx, hx.v[t]);
                const h2 dy = h2add(qy, hy.v[t]);
                const h2 dz = h2add(qz, hz.v[t]);
                h2 d = h2mul(dx, dx);
                d = h2fma(dy, dy, d);
                d = h2fma(dz, dz, d);
                if (HAS_SELF) {
                    const int j0 = jg0 + bb * 32 + r * 8 + 2 * t;
                    if (j0 == i)     d.x = (__fp16)SENT_F;
                    if (j0 + 1 == i) d.y = (__fp16)SENT_F;
                }
                c[r * 4 + t] = d;
            }
        }
        oems_sort16h(c);
        merge16h(knn, c);
    }
}

// ---------------------------------------------------------------------------
// Kernel 1: per-point mean of 16 smallest non-self squared distances.
// Block = 512 threads = 8 waves, one point per lane of wave 0's lane space
// (all waves cover the same 64 points, different j-chunks). Wave w handles
// j-chunk w (512 j's = 2 tiles). Core tile/sort/merge code byte-identical to
// the proven round-0 kernel; only JSPLIT/BLK and the f16 lst epilogue differ.
// LDS 29.7 KB -> 4 blocks/CU -> 32 waves/CU theoretical (vs round-0's 16):
// tests whether the 21 us wall-vs-VALUBusy gap is exposed ds_read latency.
// ---------------------------------------------------------------------------
__global__ __launch_bounds__(BLK, 6) void knn_kernel(const float* __restrict__ pcs,
                                                     float* __restrict__ knn_out) {
    __shared__ float4 s[JSPLIT][3][TJ / 8];       // f16 SoA x/y/z, 12 KB
    __shared__ __fp16 lst[JSPLIT][PTS][K_ + 1];   // 17.4 KB (values f16-exact)

    const int b    = blockIdx.x >> 6;             // 64 blocks per batch
    const int grp  = blockIdx.x & 63;
    const int i0   = grp * PTS;
    const int lane = threadIdx.x & 63;
    const int w    = threadIdx.x >> 6;

    const float* __restrict__ src = pcs + (size_t)b * N_ * 3;

    const int i  = i0 + lane;
    const __fp16 qxh = (__fp16)src[3 * i + 0];   // RTN, same grid as candidates
    const __fp16 qyh = (__fp16)src[3 * i + 1];
    const __fp16 qzh = (__fp16)src[3 * i + 2];
    const h2 qx = {qxh, qxh}, qy = {qyh, qyh}, qz = {qzh, qzh};

    const h2 sent = {(__fp16)SENT_F, (__fp16)SENT_F};
    h2 knn[K_];
#pragma unroll
    for (int t = 0; t < K_; ++t) knn[t] = sent;

    const int jbase = w * CHUNK;
    h2* sxw = (h2*)&s[w][0][0];
    h2* syw = (h2*)&s[w][1][0];
    h2* szw = (h2*)&s[w][2][0];

#pragma unroll 1
    for (int t0 = 0; t0 < CHUNK; t0 += TJ) {
        // ---- stage: lane l loads 4 points (3 float4 = 12 floats), converts
        //      NEGATED (RTN) to f16, writes paired h2 SoA.
        const float4* __restrict__ g4 =
            (const float4*)(src + (size_t)(jbase + t0) * 3);
        const float4 f0 = g4[3 * lane + 0];
        const float4 f1 = g4[3 * lane + 1];
        const float4 f2 = g4[3 * lane + 2];
        sxw[2 * lane + 0] = h2{(__fp16)(-f0.x), (__fp16)(-f0.w)};
        sxw[2 * lane + 1] = h2{(__fp16)(-f1.z), (__fp16)(-f2.y)};
        syw[2 * lane + 0] = h2{(__fp16)(-f0.y), (__fp16)(-f1.x)};
        syw[2 * lane + 1] = h2{(__fp16)(-f1.w), (__fp16)(-f2.z)};
        szw[2 * lane + 0] = h2{(__fp16)(-f0.z), (__fp16)(-f1.y)};
        szw[2 * lane + 1] = h2{(__fp16)(-f2.x), (__fp16)(-f2.w)};
        // wave-private quadrant; lanes lockstep within the wave, compiler
        // inserts lgkmcnt waits for the write->read dependence.

        const int jg0 = jbase + t0;
        if ((i0 >> 8) == (jg0 >> 8)) {
            process_tile<true >(&s[w][0][0], &s[w][1][0], &s[w][2][0],
                                jg0, i, qx, qy, qz, knn);
        } else {
            process_tile<false>(&s[w][0][0], &s[w][1][0], &s[w][2][0],
                                jg0, i, qx, qy, qz, knn);
        }
    }

    // ---- combine the two packed streams (lo/hi), once per wave
    float lo[K_], hi[K_];
#pragma unroll
    for (int t = 0; t < K_; ++t) { lo[t] = (float)knn[t].x; hi[t] = (float)knn[t].y; }
    merge16f(lo, hi);   // lowest 16 of 32, sorted asc

#pragma unroll
    for (int q = 0; q < K_; ++q) lst[w][lane][q] = (__fp16)lo[q];
    lst[w][lane][K_] = (__fp16)SENT_F;
    __syncthreads();

    // ---- 8-way merge of sorted lists, one thread per point (wave 0)
    if (threadIdx.x < PTS) {
        const int l = threadIdx.x;
        int p0 = 0, p1 = 0, p2 = 0, p3 = 0, p4 = 0, p5 = 0, p6 = 0, p7 = 0;
        float e0 = (float)lst[0][l][0], e1 = (float)lst[1][l][0];
        float e2 = (float)lst[2][l][0], e3 = (float)lst[3][l][0];
        float e4 = (float)lst[4][l][0], e5 = (float)lst[5][l][0];
        float e6 = (float)lst[6][l][0], e7 = (float)lst[7][l][0];
        float sm = 0.0f;
#pragma unroll
        for (int step = 0; step < K_; ++step) {
            const float m01 = fminf(e0, e1), m23 = fminf(e2, e3);
            const float m45 = fminf(e4, e5), m67 = fminf(e6, e7);
            const float m = fminf(fminf(m01, m23), fminf(m45, m67));
            sm += m;
            if (e0 == m)      { e0 = (float)lst[0][l][++p0]; }
            else if (e1 == m) { e1 = (float)lst[1][l][++p1]; }
            else if (e2 == m) { e2 = (float)lst[2][l][++p2]; }
            else if (e3 == m) { e3 = (float)lst[3][l][++p3]; }
            else if (e4 == m) { e4 = (float)lst[4][l][++p4]; }
            else if (e5 == m) { e5 = (float)lst[5][l][++p5]; }
            else if (e6 == m) { e6 = (float)lst[6][l][++p6]; }
            else              { e7 = (float)lst[7][l][++p7]; }
        }
        knn_out[b * N_ + i0 + l] = sm * (1.0f / (float)K_);
    }
}

// ---------------------------------------------------------------------------
// Block reduction helper (256 threads = 4 waves)
// ---------------------------------------------------------------------------
__device__ __forceinline__ float block_reduce_sum_256(float v, float* sbuf) {
    const int lane = threadIdx.x & 63;
    const int w    = threadIdx.x >> 6;
#pragma unroll
    for (int o = 32; o > 0; o >>= 1) v += __shfl_down(v, o, 64);
    __syncthreads();
    if (lane == 0) sbuf[w] = v;
    __syncthreads();
    return sbuf[0] + sbuf[1] + sbuf[2] + sbuf[3];
}

// ---------------------------------------------------------------------------
// Kernel 2: per-batch mean, std (two-pass), threshold, penalty partial sum,
// fused final: atomicAdd of scaled penalty into out[0] (memset to 0 first).
// ---------------------------------------------------------------------------
__global__ __launch_bounds__(256) void stats_kernel(const float* __restrict__ knn_d,
                                                    float* __restrict__ out) {
    const int b   = blockIdx.x;
    const int tid = threadIdx.x;
    const float* __restrict__ x = knn_d + (size_t)b * N_;

    __shared__ float sbuf[4];

    float v[16];
    float s = 0.0f;
#pragma unroll
    for (int t = 0; t < 16; ++t) {
        v[t] = x[tid + t * 256];
        s += v[t];
    }
    const float total = block_reduce_sum_256(s, sbuf);
    const float mu = total * (1.0f / (float)N_);

    float vs = 0.0f;
#pragma unroll
    for (int t = 0; t < 16; ++t) {
        const float d = v[t] - mu;
        vs += d * d;
    }
    const float var    = block_reduce_sum_256(vs, sbuf) * (1.0f / (float)N_);
    const float thresh = mu + ALPHA_ * sqrtf(var);

    float p = 0.0f;
#pragma unroll
    for (int t = 0; t < 16; ++t) {
        if (v[t] > thresh) p += v[t];
    }
    const float psum = block_reduce_sum_256(p, sbuf);
    if (tid == 0) atomicAdd(out, psum * (1.0f / (float)(B_ * N_)));
}

extern "C" void kernel_launch(void* const* d_in, const int* in_sizes, int n_in,
                              void* d_out, int out_size, void* d_ws, size_t ws_size,
                              hipStream_t stream) {
    const float* pcs = (const float*)d_in[0];
    float* out = (float*)d_out;

    float* knn_d = (float*)d_ws;             // B*N floats = 256 KB

    (void)hipMemsetAsync(out, 0, sizeof(float), stream);
    knn_kernel<<<B_ * (N_ / PTS), BLK, 0, stream>>>(pcs, knn_d);
    stats_kernel<<<B_, 256, 0, stream>>>(knn_d, out);
}